// Round 1
// baseline (35.090 us; speedup 1.0000x reference)
//
#include <hip/hip_runtime.h>
#include <math.h>

#define NLAB 2000
#define BATCH 1024
#define LAMBDA_SMOOTH 0.1f

// ---------------------------------------------------------------------------
// Kernel 1: fused label-conversion + transpose.
//   in : logits [BATCH][NLAB], labels [BATCH][NLAB]  (row-major)
//   out: yT [NLAB][BATCH]  (row-major) in workspace
// 64x64 tiles staged through LDS so both global read and global write are
// coalesced. Block (64,16), each thread covers 4 rows of the tile.
// ---------------------------------------------------------------------------
__global__ void convert_transpose_kernel(const float* __restrict__ logits,
                                         const float* __restrict__ labels,
                                         float* __restrict__ yT) {
    __shared__ float tile[64][65];   // +1 pad: conflict-free transpose
    const int tileJ = blockIdx.x * 64;   // label dim
    const int tileB = blockIdx.y * 64;   // batch dim
    const int tx = threadIdx.x;          // 0..63
    const int ty = threadIdx.y;          // 0..15

#pragma unroll
    for (int bi = 0; bi < 4; ++bi) {
        const int lb = ty + bi * 16;         // local batch row 0..63
        const int j  = tileJ + tx;           // global label
        const int b  = tileB + lb;           // global batch
        if (j < NLAB) {
            const int idx = b * NLAB + j;    // coalesced in tx
            const float lg  = logits[idx];
            const float lab = labels[idx];
            const float sg  = 1.0f / (1.0f + expf(-lg));
            const bool ann  = (lab == 0.0f) || (lab == 1.0f);
            const float y   = ann ? (2.0f * lab - 1.0f) : (2.0f * sg - 1.0f);
            tile[lb][tx] = y;
        }
    }
    __syncthreads();
#pragma unroll
    for (int ji = 0; ji < 4; ++ji) {
        const int lj = ty + ji * 16;         // local label col 0..63
        const int j  = tileJ + lj;           // global label
        const int b  = tileB + tx;           // global batch
        if (j < NLAB) {
            yT[j * BATCH + b] = tile[tx][lj];  // coalesced in tx
        }
    }
}

// ---------------------------------------------------------------------------
// Kernel 2: per-edge reduction. One wave (64 lanes) per edge, grid-stride
// over edges. Lanes sweep the batch dimension of the two gathered columns
// (contiguous 4 KB streams, L2/L3-resident). One fp32 partial per block.
// ---------------------------------------------------------------------------
__global__ void edge_reduce_kernel(const float* __restrict__ yT,
                                   const float* __restrict__ ew,
                                   const int* __restrict__ li,
                                   const int* __restrict__ ri,
                                   int nEdges,
                                   float* __restrict__ partials) {
    const int wave  = threadIdx.x >> 6;            // 0..3
    const int lane  = threadIdx.x & 63;
    const int wpb   = blockDim.x >> 6;             // waves per block (4)

    float acc = 0.0f;
    for (int e = blockIdx.x * wpb + wave; e < nEdges; e += gridDim.x * wpb) {
        const float* __restrict__ cl = yT + li[e] * BATCH;
        const float* __restrict__ cr = yT + ri[e] * BATCH;
        float s = 0.0f;
#pragma unroll
        for (int b0 = 0; b0 < BATCH; b0 += 64) {
            const float d = cl[b0 + lane] - cr[b0 + lane];
            s = fmaf(d, d, s);
        }
        acc += ew[e] * s;
    }

    // wave reduce (64 lanes)
#pragma unroll
    for (int off = 32; off > 0; off >>= 1)
        acc += __shfl_down(acc, off, 64);

    __shared__ float smem[8];
    if (lane == 0) smem[wave] = acc;
    __syncthreads();
    if (threadIdx.x == 0) {
        float t = 0.0f;
        for (int i = 0; i < wpb; ++i) t += smem[i];
        partials[blockIdx.x] = t;   // written unconditionally every call
    }
}

// ---------------------------------------------------------------------------
// Kernel 3: sum the block partials and scale. Single block.
// ---------------------------------------------------------------------------
__global__ void final_reduce_kernel(const float* __restrict__ partials,
                                    int n, float scale,
                                    float* __restrict__ out) {
    float s = 0.0f;
    for (int i = threadIdx.x; i < n; i += blockDim.x) s += partials[i];
#pragma unroll
    for (int off = 32; off > 0; off >>= 1)
        s += __shfl_down(s, off, 64);

    __shared__ float smem[16];
    const int wave = threadIdx.x >> 6;
    const int lane = threadIdx.x & 63;
    if (lane == 0) smem[wave] = s;
    __syncthreads();
    if (threadIdx.x == 0) {
        float t = 0.0f;
        for (int i = 0; i < (int)(blockDim.x >> 6); ++i) t += smem[i];
        out[0] = scale * t;
    }
}

// ---------------------------------------------------------------------------
extern "C" void kernel_launch(void* const* d_in, const int* in_sizes, int n_in,
                              void* d_out, int out_size, void* d_ws, size_t ws_size,
                              hipStream_t stream) {
    const float* logits = (const float*)d_in[0];
    const float* labels = (const float*)d_in[1];
    const float* ew     = (const float*)d_in[2];
    const int*   li     = (const int*)d_in[3];
    const int*   ri     = (const int*)d_in[4];
    float* out          = (float*)d_out;

    const int nEdges = in_sizes[2];

    // workspace layout
    float* yT       = (float*)d_ws;                          // NLAB*BATCH floats (8 MB)
    float* partials = (float*)((char*)d_ws + (size_t)NLAB * BATCH * sizeof(float));

    // K1: convert + transpose
    dim3 b1(64, 16);
    dim3 g1((NLAB + 63) / 64, BATCH / 64);
    convert_transpose_kernel<<<g1, b1, 0, stream>>>(logits, labels, yT);

    // K2: edge reduction
    const int NB2 = 2048;          // 2048 partials, 4 waves/block
    edge_reduce_kernel<<<NB2, 256, 0, stream>>>(yT, ew, li, ri, nEdges, partials);

    // K3: final sum + scale
    const float scale = LAMBDA_SMOOTH / ((float)BATCH * (float)nEdges);
    final_reduce_kernel<<<1, 1024, 0, stream>>>(partials, NB2, scale, out);
}

// Round 2
// 33.769 us; speedup vs baseline: 1.0391x; 1.0391x over previous
//
#include <hip/hip_runtime.h>
#include <math.h>

#define NLAB 2000
#define BATCH 1024
#define LAMBDA_SMOOTH 0.1f

#define NCHUNK 8        // batch chunks; 1 per XCD (blockIdx % 8 ~ XCD id)
#define CHUNKB 128      // batches per chunk; slice = 2000*128*4B = 1 MB -> fits XCD L2
#define NB2 2048        // K2 blocks = 256 edge-slices x 8 chunks; fills 8192 wave slots

// ---------------------------------------------------------------------------
// Kernel 1: fused label-conversion + transpose.
//   in : logits [BATCH][NLAB], labels [BATCH][NLAB]  (row-major)
//   out: yT [NLAB][BATCH]  (row-major) in workspace
// ---------------------------------------------------------------------------
__global__ void convert_transpose_kernel(const float* __restrict__ logits,
                                         const float* __restrict__ labels,
                                         float* __restrict__ yT) {
    __shared__ float tile[64][65];   // +1 pad: conflict-free transpose
    const int tileJ = blockIdx.x * 64;   // label dim
    const int tileB = blockIdx.y * 64;   // batch dim
    const int tx = threadIdx.x;          // 0..63
    const int ty = threadIdx.y;          // 0..15

#pragma unroll
    for (int bi = 0; bi < 4; ++bi) {
        const int lb = ty + bi * 16;         // local batch row 0..63
        const int j  = tileJ + tx;           // global label
        const int b  = tileB + lb;           // global batch
        if (j < NLAB) {
            const int idx = b * NLAB + j;    // coalesced in tx
            const float lg  = logits[idx];
            const float lab = labels[idx];
            const float sg  = 1.0f / (1.0f + expf(-lg));
            const bool ann  = (lab == 0.0f) || (lab == 1.0f);
            const float y   = ann ? (2.0f * lab - 1.0f) : (2.0f * sg - 1.0f);
            tile[lb][tx] = y;
        }
    }
    __syncthreads();
#pragma unroll
    for (int ji = 0; ji < 4; ++ji) {
        const int lj = ty + ji * 16;         // local label col 0..63
        const int j  = tileJ + lj;           // global label
        const int b  = tileB + tx;           // global batch
        if (j < NLAB) {
            yT[j * BATCH + b] = tile[tx][lj];  // coalesced in tx
        }
    }
}

// ---------------------------------------------------------------------------
// Kernel 2: per-edge reduction, L2-chunked over batch.
//   chunk = blockIdx & 7 -> one 128-batch slice per XCD (1 MB, L2-resident).
//   Each wave owns a CONTIGUOUS edge range; left_idx is sorted (np.nonzero),
//   so the left column is register-cached across same-label runs.
//   Each lane covers batch elements (lane, lane+64) of its chunk.
// ---------------------------------------------------------------------------
__global__ void edge_reduce_kernel(const float* __restrict__ yT,
                                   const float* __restrict__ ew,
                                   const int* __restrict__ li,
                                   const int* __restrict__ ri,
                                   int nEdges,
                                   float* __restrict__ partials) {
    const int chunk  = blockIdx.x & (NCHUNK - 1);
    const int slice  = blockIdx.x >> 3;            // edge-slice id
    const int nSlice = gridDim.x >> 3;
    const int wave   = threadIdx.x >> 6;           // 0..3
    const int lane   = threadIdx.x & 63;
    const int bbase  = chunk * CHUNKB + lane;      // element 0; element 1 at +64

    const int nW  = nSlice * 4;                    // waves sweeping this chunk
    const int wid = slice * 4 + wave;
    const int per = (nEdges + nW - 1) / nW;
    const int e0  = wid * per;
    int e1 = e0 + per; if (e1 > nEdges) e1 = nEdges;

    float acc0 = 0.0f, acc1 = 0.0f;
    int   curL = -1;
    float yl0 = 0.0f, yl1 = 0.0f;
    for (int e = e0; e < e1; ++e) {
        const int l = li[e];
        if (l != curL) {                            // wave-uniform, rare (~1/20)
            const float* __restrict__ cl = yT + (size_t)l * BATCH + bbase;
            yl0 = cl[0];
            yl1 = cl[64];
            curL = l;
        }
        const float* __restrict__ cr = yT + (size_t)ri[e] * BATCH + bbase;
        const float yr0 = cr[0];
        const float yr1 = cr[64];
        const float w   = ew[e];
        const float d0  = yl0 - yr0;
        const float d1  = yl1 - yr1;
        acc0 = fmaf(w * d0, d0, acc0);
        acc1 = fmaf(w * d1, d1, acc1);
    }
    float acc = acc0 + acc1;

#pragma unroll
    for (int off = 32; off > 0; off >>= 1)
        acc += __shfl_down(acc, off, 64);

    __shared__ float smem[4];
    if (lane == 0) smem[wave] = acc;
    __syncthreads();
    if (threadIdx.x == 0) {
        partials[blockIdx.x] = smem[0] + smem[1] + smem[2] + smem[3];
    }
}

// ---------------------------------------------------------------------------
// Kernel 3: sum the block partials and scale. Single block.
// ---------------------------------------------------------------------------
__global__ void final_reduce_kernel(const float* __restrict__ partials,
                                    int n, float scale,
                                    float* __restrict__ out) {
    float s = 0.0f;
    for (int i = threadIdx.x; i < n; i += blockDim.x) s += partials[i];
#pragma unroll
    for (int off = 32; off > 0; off >>= 1)
        s += __shfl_down(s, off, 64);

    __shared__ float smem[16];
    const int wave = threadIdx.x >> 6;
    const int lane = threadIdx.x & 63;
    if (lane == 0) smem[wave] = s;
    __syncthreads();
    if (threadIdx.x == 0) {
        float t = 0.0f;
        for (int i = 0; i < (int)(blockDim.x >> 6); ++i) t += smem[i];
        out[0] = scale * t;
    }
}

// ---------------------------------------------------------------------------
extern "C" void kernel_launch(void* const* d_in, const int* in_sizes, int n_in,
                              void* d_out, int out_size, void* d_ws, size_t ws_size,
                              hipStream_t stream) {
    const float* logits = (const float*)d_in[0];
    const float* labels = (const float*)d_in[1];
    const float* ew     = (const float*)d_in[2];
    const int*   li     = (const int*)d_in[3];
    const int*   ri     = (const int*)d_in[4];
    float* out          = (float*)d_out;

    const int nEdges = in_sizes[2];

    // workspace layout
    float* yT       = (float*)d_ws;                          // NLAB*BATCH floats (8 MB)
    float* partials = (float*)((char*)d_ws + (size_t)NLAB * BATCH * sizeof(float));

    // K1: convert + transpose
    dim3 b1(64, 16);
    dim3 g1((NLAB + 63) / 64, BATCH / 64);
    convert_transpose_kernel<<<g1, b1, 0, stream>>>(logits, labels, yT);

    // K2: edge reduction (L2-chunked)
    edge_reduce_kernel<<<NB2, 256, 0, stream>>>(yT, ew, li, ri, nEdges, partials);

    // K3: final sum + scale
    const float scale = LAMBDA_SMOOTH / ((float)BATCH * (float)nEdges);
    final_reduce_kernel<<<1, 1024, 0, stream>>>(partials, NB2, scale, out);
}

// Round 3
// 28.948 us; speedup vs baseline: 1.2121x; 1.1665x over previous
//
#include <hip/hip_runtime.h>
#include <math.h>

#define NLAB 2000
#define BATCH 1024
#define LAMBDA_SMOOTH 0.1f

#define RPG 8            // batch rows per group
#define NRG 128          // row groups (1024/8)
#define ES  8            // edge slices -> K2 grid = 128*8 = 1024 blocks
#define IMG_U16 18000    // padded image: (2000 + 2000/8)*8 u16 = 36000 B
#define IMG_V4  2250     // same in uint4

// u16 slot of (label l, row 0): 8 u16 per label + one 16B pad granule per 8 labels
__device__ __forceinline__ int slotOf(int l) { return (l + (l >> 3)) << 3; }

__device__ __forceinline__ ushort f2bf(float f) {   // round-to-nearest-even bf16
    unsigned u = __float_as_uint(f);
    return (ushort)((u + 0x7fffu + ((u >> 16) & 1u)) >> 16);
}
__device__ __forceinline__ float bf_lo(unsigned u) { return __uint_as_float(u << 16); }
__device__ __forceinline__ float bf_hi(unsigned u) { return __uint_as_float(u & 0xffff0000u); }

// ---------------------------------------------------------------------------
// K1: convert + pack-transpose. grid 256: rg = bid>>1, half = bid&1.
// Each block: 8 batch rows x 1000 labels -> half image (18000 B) staged in LDS,
// streamed out linearly (coalesced 16 B/lane).
// ---------------------------------------------------------------------------
__global__ __launch_bounds__(256) void convert_pack_kernel(
        const float* __restrict__ logits, const float* __restrict__ labels,
        uint4* __restrict__ yPack) {
    __shared__ uint4 shv[1125];                 // 18000 B
    ushort* sh = (ushort*)shv;
    const int rg   = blockIdx.x >> 1;
    const int h    = blockIdx.x & 1;
    const int tid  = threadIdx.x;
    const int ubase = h * 9000;                 // u16 offset of this half image

    for (int lo = tid; lo < 1000; lo += 256) {
        const int l  = h * 1000 + lo;
        const int us = slotOf(l) - ubase;       // local u16 slot, in [0, 9000)
#pragma unroll
        for (int r = 0; r < RPG; ++r) {
            const int idx = (rg * RPG + r) * NLAB + l;   // coalesced in lo
            const float lg  = logits[idx];
            const float lab = labels[idx];
            const float sg  = 1.0f / (1.0f + __expf(-lg));
            const bool ann  = (lab == 0.0f) || (lab == 1.0f);
            const float y   = ann ? (2.0f * lab - 1.0f) : (2.0f * sg - 1.0f);
            sh[us + r] = f2bf(y);
        }
    }
    __syncthreads();
    uint4* dst = yPack + (size_t)rg * IMG_V4 + (size_t)h * 1125;
    for (int i = tid; i < 1125; i += 256) dst[i] = shv[i];
}

// ---------------------------------------------------------------------------
// K2: edge reduction. grid 1024: es = bid&7 (edge slice), rg = bid>>3.
// Block streams its 36 KB image into LDS, then each lane owns an edge:
// coalesced index loads + two ds_read_b128 gathers (8 rows/read, padded).
// No branches in the loop -> compiler pipelines freely; 16 waves/CU.
// ---------------------------------------------------------------------------
__global__ __launch_bounds__(256) void edge_reduce_kernel(
        const uint4* __restrict__ yPack, const float* __restrict__ ew,
        const int* __restrict__ li, const int* __restrict__ ri,
        int nEdges, float* __restrict__ partials) {
    __shared__ uint4 shv[IMG_V4];               // 36000 B
    __shared__ float red[4];
    const int es  = blockIdx.x & (ES - 1);
    const int rg  = blockIdx.x >> 3;
    const int tid = threadIdx.x;

    const uint4* src = yPack + (size_t)rg * IMG_V4;
    for (int i = tid; i < IMG_V4; i += 256) shv[i] = src[i];
    __syncthreads();
    const ushort* sh = (const ushort*)shv;

    const int per = (nEdges + ES - 1) / ES;
    const int e0  = es * per;
    int e1 = e0 + per; if (e1 > nEdges) e1 = nEdges;

    float acc = 0.0f;
    for (int e = e0 + tid; e < e1; e += 256) {
        const int  l = li[e];
        const int  r = ri[e];
        const float w = ew[e];
        const uint4 A = *(const uint4*)(sh + slotOf(l));   // 8 rows of left col
        const uint4 B = *(const uint4*)(sh + slotOf(r));   // 8 rows of right col
        float s = 0.0f;
        float d;
        d = bf_lo(A.x) - bf_lo(B.x); s = fmaf(d, d, s);
        d = bf_hi(A.x) - bf_hi(B.x); s = fmaf(d, d, s);
        d = bf_lo(A.y) - bf_lo(B.y); s = fmaf(d, d, s);
        d = bf_hi(A.y) - bf_hi(B.y); s = fmaf(d, d, s);
        d = bf_lo(A.z) - bf_lo(B.z); s = fmaf(d, d, s);
        d = bf_hi(A.z) - bf_hi(B.z); s = fmaf(d, d, s);
        d = bf_lo(A.w) - bf_lo(B.w); s = fmaf(d, d, s);
        d = bf_hi(A.w) - bf_hi(B.w); s = fmaf(d, d, s);
        acc = fmaf(w, s, acc);
    }

#pragma unroll
    for (int off = 32; off > 0; off >>= 1)
        acc += __shfl_down(acc, off, 64);
    if ((tid & 63) == 0) red[tid >> 6] = acc;
    __syncthreads();
    if (tid == 0)
        partials[blockIdx.x] = red[0] + red[1] + red[2] + red[3];
}

// ---------------------------------------------------------------------------
// K3: sum partials, scale. Single block.
// ---------------------------------------------------------------------------
__global__ __launch_bounds__(1024) void final_reduce_kernel(
        const float* __restrict__ partials, int n, float scale,
        float* __restrict__ out) {
    float s = 0.0f;
    for (int i = threadIdx.x; i < n; i += blockDim.x) s += partials[i];
#pragma unroll
    for (int off = 32; off > 0; off >>= 1)
        s += __shfl_down(s, off, 64);

    __shared__ float smem[16];
    const int wave = threadIdx.x >> 6;
    const int lane = threadIdx.x & 63;
    if (lane == 0) smem[wave] = s;
    __syncthreads();
    if (threadIdx.x == 0) {
        float t = 0.0f;
        for (int i = 0; i < (int)(blockDim.x >> 6); ++i) t += smem[i];
        out[0] = scale * t;
    }
}

// ---------------------------------------------------------------------------
extern "C" void kernel_launch(void* const* d_in, const int* in_sizes, int n_in,
                              void* d_out, int out_size, void* d_ws, size_t ws_size,
                              hipStream_t stream) {
    const float* logits = (const float*)d_in[0];
    const float* labels = (const float*)d_in[1];
    const float* ew     = (const float*)d_in[2];
    const int*   li     = (const int*)d_in[3];
    const int*   ri     = (const int*)d_in[4];
    float* out          = (float*)d_out;

    const int nEdges = in_sizes[2];

    // workspace: yPack images (128 * 36000 B = 4.6 MB), then partials
    uint4* yPack    = (uint4*)d_ws;
    float* partials = (float*)((char*)d_ws + (size_t)NRG * IMG_U16 * sizeof(ushort));

    convert_pack_kernel<<<256, 256, 0, stream>>>(logits, labels, yPack);

    const int NB2 = NRG * ES;   // 1024
    edge_reduce_kernel<<<NB2, 256, 0, stream>>>(yPack, ew, li, ri, nEdges, partials);

    const float scale = LAMBDA_SMOOTH / ((float)BATCH * (float)nEdges);
    final_reduce_kernel<<<1, 1024, 0, stream>>>(partials, NB2, scale, out);
}